// Round 4
// baseline (167.441 us; speedup 1.0000x reference)
//
#include <hip/hip_runtime.h>
#include <hip/hip_bf16.h>
#include <stdint.h>
#include <math.h>

// SelfAttention: B=4, S=4096, DK=768, H=64.  k uses q's projection (source bug),
// scale = 768^-0.5 folded as 768^-0.25 into stored q (used for both sides).
// ws layout: q_bf16 [16384][64] (2MB) | vT_bf16 [4][64][4096] (2MB)

typedef unsigned short u16;
typedef __attribute__((ext_vector_type(8))) short bf16x8;
typedef __attribute__((ext_vector_type(4))) float f32x4;

#define MFMA16(a,b,c) __builtin_amdgcn_mfma_f32_16x16x32_bf16((a),(b),(c),0,0,0)

__device__ __forceinline__ u16 f2bf(float f) {
  union { float f; uint32_t u; } v; v.f = f;
  uint32_t u = v.u;
  return (u16)((u + 0x7FFFu + ((u >> 16) & 1u)) >> 16);   // RNE
}

// Read an 8-bf16 MFMA fragment from a [64 rows][64 cols] bf16 LDS tile with
// XOR swizzle (byte ^= (row&7)<<4  ==  u16 idx ^= (row&7)<<3).
__device__ __forceinline__ bf16x8 ldsfrag(const u16* lds, int row, int k) {
  return *(const bf16x8*)(lds + row * 64 + (k ^ ((row & 7) << 3)));
}

__device__ __forceinline__ void gload_lds16(const void* g, void* l) {
  __builtin_amdgcn_global_load_lds(
      (__attribute__((address_space(1))) void*)g,
      (__attribute__((address_space(3))) void*)l, 16, 0, 0);
}

// ---------------- Kernel 1: projections -----------------------------------
// grid 256 x 256thr. Block = 64 s-rows. Waves 0-1: q = x*Wq^T (row-major out).
// Waves 2-3: vT = (x*Wv^T)^T computed directly as Wv * x^T (row-major in h).
__global__ __launch_bounds__(256) void proj_k(
    const float* __restrict__ x, const float* __restrict__ Wq,
    const float* __restrict__ bq, const float* __restrict__ Wv,
    const float* __restrict__ bv, u16* __restrict__ qbf,
    u16* __restrict__ vtbf, float qscale)
{
  __shared__ __align__(16) u16 xs[64 * 64];
  __shared__ __align__(16) u16 wqs[64 * 64];
  __shared__ __align__(16) u16 wvs[64 * 64];
  const int tid = threadIdx.x;
  const int lane = tid & 63;
  const int w = tid >> 6;
  const int l15 = lane & 15, lg = lane >> 4;
  const int s0 = blockIdx.x * 64;          // global row base in [0,16384)

  f32x4 acc[2][4];
#pragma unroll
  for (int i = 0; i < 2; i++)
#pragma unroll
    for (int n = 0; n < 4; n++) acc[i][n] = (f32x4){0.f, 0.f, 0.f, 0.f};

  const int srow = tid >> 2;               // staging: row 0..63
  const int scol = (tid & 3) << 4;         // col 0,16,32,48

  for (int ks = 0; ks < 12; ++ks) {
    const int k0 = ks << 6;
    if (ks) __syncthreads();               // prev-step tile reads done
    // stage x, Wq, Wv 64x64 fp32 -> bf16 swizzled tiles (16 floats/thread each)
    {
      const float* srcs[3] = { x + (size_t)(s0 + srow) * 768 + k0 + scol,
                               Wq + (size_t)srow * 768 + k0 + scol,
                               Wv + (size_t)srow * 768 + k0 + scol };
      u16* tiles[3] = { xs, wqs, wvs };
#pragma unroll
      for (int tset = 0; tset < 3; ++tset) {
        const float4* s4 = (const float4*)srcs[tset];
        float4 a = s4[0], b = s4[1], c = s4[2], d = s4[3];
        bf16x8 lo, hi;
        lo[0] = (short)f2bf(a.x); lo[1] = (short)f2bf(a.y);
        lo[2] = (short)f2bf(a.z); lo[3] = (short)f2bf(a.w);
        lo[4] = (short)f2bf(b.x); lo[5] = (short)f2bf(b.y);
        lo[6] = (short)f2bf(b.z); lo[7] = (short)f2bf(b.w);
        hi[0] = (short)f2bf(c.x); hi[1] = (short)f2bf(c.y);
        hi[2] = (short)f2bf(c.z); hi[3] = (short)f2bf(c.w);
        hi[4] = (short)f2bf(d.x); hi[5] = (short)f2bf(d.y);
        hi[6] = (short)f2bf(d.z); hi[7] = (short)f2bf(d.w);
        const int xsw = (srow & 7) << 3;
        *(bf16x8*)(tiles[tset] + srow * 64 + (scol ^ xsw)) = lo;
        *(bf16x8*)(tiles[tset] + srow * 64 + ((scol + 8) ^ xsw)) = hi;
      }
    }
    __syncthreads();
#pragma unroll
    for (int kk = 0; kk < 2; ++kk) {
      const int k = kk * 32 + lg * 8;
      if (w < 2) {                                  // q GEMM: A=x, B=Wq(^T)
        bf16x8 a0 = ldsfrag(xs, (2 * w + 0) * 16 + l15, k);
        bf16x8 a1 = ldsfrag(xs, (2 * w + 1) * 16 + l15, k);
#pragma unroll
        for (int n = 0; n < 4; n++) {
          bf16x8 bb = ldsfrag(wqs, n * 16 + l15, k);
          acc[0][n] = MFMA16(a0, bb, acc[0][n]);
          acc[1][n] = MFMA16(a1, bb, acc[1][n]);
        }
      } else {                                      // vT GEMM: A=Wv, B=x^T
        bf16x8 a0 = ldsfrag(wvs, (2 * (w - 2) + 0) * 16 + l15, k);
        bf16x8 a1 = ldsfrag(wvs, (2 * (w - 2) + 1) * 16 + l15, k);
#pragma unroll
        for (int n = 0; n < 4; n++) {
          bf16x8 bb = ldsfrag(xs, n * 16 + l15, k);
          acc[0][n] = MFMA16(a0, bb, acc[0][n]);
          acc[1][n] = MFMA16(a1, bb, acc[1][n]);
        }
      }
    }
  }

  if (w < 2) {   // q epilogue: C row = s-local, col = h
#pragma unroll
    for (int i = 0; i < 2; i++)
#pragma unroll
      for (int n = 0; n < 4; n++) {
        const int h = n * 16 + l15;
        const float bias = bq[h];
#pragma unroll
        for (int r = 0; r < 4; r++) {
          const int sg = s0 + (2 * w + i) * 16 + lg * 4 + r;
          qbf[(size_t)sg * 64 + h] = f2bf((acc[i][n][r] + bias) * qscale);
        }
      }
  } else {       // vT epilogue: C row = h, col = s-local
    const int b = s0 >> 12;
    const int sloc = s0 & 4095;
#pragma unroll
    for (int i = 0; i < 2; i++)
#pragma unroll
      for (int n = 0; n < 4; n++) {
        const int scg = sloc + n * 16 + l15;
#pragma unroll
        for (int r = 0; r < 4; r++) {
          const int h = (2 * (w - 2) + i) * 16 + lg * 4 + r;
          vtbf[(size_t)(b * 64 + h) * 4096 + scg] = f2bf(acc[i][n][r] + bv[h]);
        }
      }
  }
}

// ---------------- Kernel 2: flash attention (no-max softmax) ---------------
// grid (64,4) x 512thr. 8 waves: wq=w&3 owns 16 q rows, wk=w>>2 owns a 32-kv
// half of each 64-kv tile. K tile [kv][d] & V^T tile [d][kv] staged via
// global_load_lds with XOR swizzle folded into the *source* address.
__global__ __launch_bounds__(512) void attn_k(
    const u16* __restrict__ qbf, const u16* __restrict__ vtbf,
    float* __restrict__ out)
{
  __shared__ __align__(16) u16 smem[8192 + 8192 + 8 * 640];
  u16* kt0 = smem;                 // [2][4096] K double-buffer
  u16* vt0 = smem + 8192;          // [2][4096] V^T double-buffer
  u16* pl  = smem + 16384;         // [8][16][40] per-wave P
  const int tid = threadIdx.x;
  const int lane = tid & 63;
  const int w = tid >> 6;
  const int wq = w & 3, wk = w >> 2;
  const int l15 = lane & 15, lg = lane >> 4;
  const int b = blockIdx.y;
  const int q0 = blockIdx.x << 6;

  bf16x8 qf[2];
  {
    const u16* qr = qbf + (size_t)(b * 4096 + q0 + wq * 16 + l15) * 64 + lg * 8;
    qf[0] = *(const bf16x8*)(qr);
    qf[1] = *(const bf16x8*)(qr + 32);
  }

  f32x4 oacc[4];
#pragma unroll
  for (int i = 0; i < 4; i++) oacc[i] = (f32x4){0.f, 0.f, 0.f, 0.f};
  float lacc[4] = {0.f, 0.f, 0.f, 0.f};

  // staging addresses (16B per thread per tile per tensor)
  const int o = tid << 4;                       // LDS byte offset 0..8191
  const int krow = o >> 7;                      // row (kv for K, d for V^T)
  const int ksw = o ^ ((krow & 7) << 4);        // pre-swizzled source offset
  const char* kbase = (const char*)qbf + (size_t)(b * 4096) * 128;
  const char* vbase = (const char*)vtbf + (size_t)(b * 64 + krow) * 8192 + (ksw & 127);
  char* ldst_k = (char*)kt0 + w * 1024;         // wave-uniform LDS dest
  char* ldst_v = (char*)vt0 + w * 1024;

  const int NT = 64;
  gload_lds16(kbase + ksw, ldst_k);
  gload_lds16(vbase, ldst_v);

  for (int t = 0; t < NT; ++t) {
    const int buf = t & 1;
    __syncthreads();                            // tile t staged; buf^1 free
    if (t + 1 < NT) {
      const int nb = (t + 1) & 1;
      gload_lds16(kbase + (size_t)(t + 1) * 8192 + ksw, ldst_k + nb * 8192);
      gload_lds16(vbase + (t + 1) * 128, ldst_v + nb * 8192);
    }
    const u16* kt = kt0 + buf * 4096;
    const u16* vt = vt0 + buf * 4096;

    // QK^T: S[16 q][32 kv of this half]
    f32x4 sc0 = (f32x4){0.f, 0.f, 0.f, 0.f}, sc1 = sc0;
#pragma unroll
    for (int j = 0; j < 2; j++) {
      const int dk = j * 32 + lg * 8;
      bf16x8 k0f = ldsfrag(kt, wk * 32 + l15, dk);
      bf16x8 k1f = ldsfrag(kt, wk * 32 + 16 + l15, dk);
      sc0 = MFMA16(qf[j], k0f, sc0);
      sc1 = MFMA16(qf[j], k1f, sc1);
    }
    // exp (scores bounded ~4 -> no max subtraction) + row-sum over 16 lanes
    float p0[4], p1[4], rs[4];
#pragma unroll
    for (int r = 0; r < 4; r++) {
      p0[r] = __expf(sc0[r]);
      p1[r] = __expf(sc1[r]);
      rs[r] = p0[r] + p1[r];
    }
#pragma unroll
    for (int m = 1; m < 16; m <<= 1)
#pragma unroll
      for (int r = 0; r < 4; r++) rs[r] += __shfl_xor(rs[r], m, 64);
#pragma unroll
    for (int r = 0; r < 4; r++) lacc[r] += rs[r];
    // P: C-frag layout -> LDS -> A-frag layout
    u16* pw = pl + w * 640;
#pragma unroll
    for (int r = 0; r < 4; r++) {
      pw[(lg * 4 + r) * 40 + l15]      = f2bf(p0[r]);
      pw[(lg * 4 + r) * 40 + 16 + l15] = f2bf(p1[r]);
    }
    asm volatile("s_waitcnt lgkmcnt(0)" ::: "memory");
    bf16x8 pf = *(const bf16x8*)(pw + l15 * 40 + lg * 8);
    // PV: O[16 q][64 d] += P[16x32] * V[32x64]
#pragma unroll
    for (int db = 0; db < 4; ++db) {
      bf16x8 vf = ldsfrag(vt, db * 16 + l15, wk * 32 + lg * 8);
      oacc[db] = MFMA16(pf, vf, oacc[db]);
    }
  }

  // combine the two kv-halves, normalize, store
  __syncthreads();
  float* oc = (float*)smem;                 // [4][16][68]
  float* lc = oc + 4 * 16 * 68;             // [4][16]
  if (wk == 1) {
#pragma unroll
    for (int db = 0; db < 4; ++db)
#pragma unroll
      for (int r = 0; r < 4; r++)
        oc[(wq * 16 + lg * 4 + r) * 68 + db * 16 + l15] = oacc[db][r];
#pragma unroll
    for (int r = 0; r < 4; r++) lc[wq * 16 + lg * 4 + r] = lacc[r];
  }
  __syncthreads();
  if (wk == 0) {
#pragma unroll
    for (int db = 0; db < 4; ++db)
#pragma unroll
      for (int r = 0; r < 4; r++) {
        const int row = lg * 4 + r;
        const float ov = oacc[db][r] + oc[(wq * 16 + row) * 68 + db * 16 + l15];
        const float lt = lacc[r] + lc[wq * 16 + row];
        out[(size_t)(b * 4096 + q0 + wq * 16 + row) * 64 + db * 16 + l15] = ov / lt;
      }
  }
}

extern "C" void kernel_launch(void* const* d_in, const int* in_sizes, int n_in,
                              void* d_out, int out_size, void* d_ws, size_t ws_size,
                              hipStream_t stream) {
  const float* x  = (const float*)d_in[0];
  const float* Wq = (const float*)d_in[1];
  const float* bq = (const float*)d_in[2];
  const float* Wv = (const float*)d_in[3];
  const float* bv = (const float*)d_in[4];
  float* out = (float*)d_out;
  u16* qbf  = (u16*)d_ws;                       // 2 MB
  u16* vtbf = qbf + (size_t)16384 * 64;         // 2 MB
  const float qscale = 1.0f / sqrtf(sqrtf(768.0f));   // 768^-0.25 (both QK sides)
  proj_k<<<dim3(256), dim3(256), 0, stream>>>(x, Wq, bq, Wv, bv, qbf, vtbf, qscale);
  attn_k<<<dim3(64, 4), dim3(512), 0, stream>>>(qbf, vtbf, out);
}

// Round 5
// 165.619 us; speedup vs baseline: 1.0110x; 1.0110x over previous
//
#include <hip/hip_runtime.h>
#include <hip/hip_bf16.h>
#include <stdint.h>
#include <math.h>

// SelfAttention: B=4, S=4096, DK=768, H=64.  k uses q's projection (source bug),
// scale = 768^-0.5 folded as 768^-0.25 into stored q (used for both sides).
// ws layout: q_bf16 [16384][64] (2MB) | vT_bf16 [4][64][4096] (2MB)

typedef unsigned short u16;
typedef __attribute__((ext_vector_type(8))) short bf16x8;
typedef __attribute__((ext_vector_type(4))) float f32x4;

#define MFMA16(a,b,c) __builtin_amdgcn_mfma_f32_16x16x32_bf16((a),(b),(c),0,0,0)

__device__ __forceinline__ u16 f2bf(float f) {
  union { float f; uint32_t u; } v; v.f = f;
  uint32_t u = v.u;
  return (u16)((u + 0x7FFFu + ((u >> 16) & 1u)) >> 16);   // RNE
}

// Read an 8-bf16 MFMA fragment from a [64 rows][64 cols] bf16 LDS tile with
// XOR swizzle (byte ^= (row&7)<<4  ==  u16 idx ^= (row&7)<<3).
__device__ __forceinline__ bf16x8 ldsfrag(const u16* lds, int row, int k) {
  return *(const bf16x8*)(lds + row * 64 + (k ^ ((row & 7) << 3)));
}

__device__ __forceinline__ void gload_lds16(const void* g, void* l) {
  __builtin_amdgcn_global_load_lds(
      (__attribute__((address_space(1))) void*)g,
      (__attribute__((address_space(3))) void*)l, 16, 0, 0);
}

// 12 float4 = one 64x64 fp32 k-chunk's worth per thread (x, Wq, Wv: 16 floats each)
struct Regs { float4 r[12]; };

__device__ __forceinline__ void issue_loads(Regs& R, const float* xp,
                                            const float* qp, const float* vp,
                                            int ks) {
  const float4* a = (const float4*)(xp + (ks << 6));
  const float4* b = (const float4*)(qp + (ks << 6));
  const float4* c = (const float4*)(vp + (ks << 6));
  R.r[0] = a[0]; R.r[1] = a[1]; R.r[2] = a[2]; R.r[3] = a[3];
  R.r[4] = b[0]; R.r[5] = b[1]; R.r[6] = b[2]; R.r[7] = b[3];
  R.r[8] = c[0]; R.r[9] = c[1]; R.r[10] = c[2]; R.r[11] = c[3];
}

__device__ __forceinline__ void cvt8(const float4& a, const float4& b, bf16x8& o) {
  o[0] = (short)f2bf(a.x); o[1] = (short)f2bf(a.y);
  o[2] = (short)f2bf(a.z); o[3] = (short)f2bf(a.w);
  o[4] = (short)f2bf(b.x); o[5] = (short)f2bf(b.y);
  o[6] = (short)f2bf(b.z); o[7] = (short)f2bf(b.w);
}

__device__ __forceinline__ void cvt_store(const Regs& R, u16* xrow, u16* qrow,
                                          u16* vrow, int scol, int xsw) {
  bf16x8 lo, hi;
  cvt8(R.r[0], R.r[1], lo);  cvt8(R.r[2], R.r[3], hi);
  *(bf16x8*)(xrow + (scol ^ xsw)) = lo;
  *(bf16x8*)(xrow + ((scol + 8) ^ xsw)) = hi;
  cvt8(R.r[4], R.r[5], lo);  cvt8(R.r[6], R.r[7], hi);
  *(bf16x8*)(qrow + (scol ^ xsw)) = lo;
  *(bf16x8*)(qrow + ((scol + 8) ^ xsw)) = hi;
  cvt8(R.r[8], R.r[9], lo);  cvt8(R.r[10], R.r[11], hi);
  *(bf16x8*)(vrow + (scol ^ xsw)) = lo;
  *(bf16x8*)(vrow + ((scol + 8) ^ xsw)) = hi;
}

// ---------------- Kernel 1: projections -----------------------------------
// grid 256 x 256thr. Waves 0-1: q = x*Wq^T. Waves 2-3: vT = Wv*x^T.
// Distance-2 register prefetch, LDS double-buffer, ONE lgkm-only barrier/step.
__global__ __launch_bounds__(256) void proj_k(
    const float* __restrict__ x, const float* __restrict__ Wq,
    const float* __restrict__ bq, const float* __restrict__ Wv,
    const float* __restrict__ bv, u16* __restrict__ qbf,
    u16* __restrict__ vtbf, float qscale)
{
  __shared__ __align__(16) u16 xs[2][4096];
  __shared__ __align__(16) u16 wqs[2][4096];
  __shared__ __align__(16) u16 wvs[2][4096];
  const int tid = threadIdx.x;
  const int lane = tid & 63;
  const int w = tid >> 6;
  const int l15 = lane & 15, lg = lane >> 4;
  const int s0 = blockIdx.x * 64;

  f32x4 acc[2][4];
#pragma unroll
  for (int i = 0; i < 2; i++)
#pragma unroll
    for (int n = 0; n < 4; n++) acc[i][n] = (f32x4){0.f, 0.f, 0.f, 0.f};

  const int srow = tid >> 2;
  const int scol = (tid & 3) << 4;
  const int xsw = (srow & 7) << 3;
  const float* xsrc = x + (size_t)(s0 + srow) * 768 + scol;
  const float* qsrc = Wq + (size_t)srow * 768 + scol;
  const float* vsrc = Wv + (size_t)srow * 768 + scol;

  Regs A, B;
  issue_loads(A, xsrc, qsrc, vsrc, 0);
  issue_loads(B, xsrc, qsrc, vsrc, 1);
  asm volatile("s_waitcnt vmcnt(12)" ::: "memory");   // loads(0) done
  cvt_store(A, &xs[0][srow * 64], &wqs[0][srow * 64], &wvs[0][srow * 64], scol, xsw);

#pragma unroll
  for (int ks = 0; ks < 12; ++ks) {
    const int b = ks & 1;
    if (ks + 2 < 12) {                     // distance-2 prefetch into free bank
      if (b) issue_loads(B, xsrc, qsrc, vsrc, ks + 2);
      else   issue_loads(A, xsrc, qsrc, vsrc, ks + 2);
    }
    asm volatile("s_waitcnt lgkmcnt(0)" ::: "memory"); // my buf[b] writes done
    __builtin_amdgcn_s_barrier();                      // buf[b] visible to all
    __builtin_amdgcn_sched_barrier(0);

    const u16* xt = xs[b];
    const u16* qt = wqs[b];
    const u16* vt = wvs[b];
#pragma unroll
    for (int kk = 0; kk < 2; ++kk) {
      const int k = kk * 32 + lg * 8;
      if (w < 2) {                                  // q GEMM: A=x, B=Wq
        bf16x8 a0 = ldsfrag(xt, (2 * w + 0) * 16 + l15, k);
        bf16x8 a1 = ldsfrag(xt, (2 * w + 1) * 16 + l15, k);
#pragma unroll
        for (int n = 0; n < 4; n++) {
          bf16x8 bb = ldsfrag(qt, n * 16 + l15, k);
          acc[0][n] = MFMA16(a0, bb, acc[0][n]);
          acc[1][n] = MFMA16(a1, bb, acc[1][n]);
        }
      } else {                                      // vT GEMM: A=Wv, B=x^T
        bf16x8 a0 = ldsfrag(vt, (2 * (w - 2) + 0) * 16 + l15, k);
        bf16x8 a1 = ldsfrag(vt, (2 * (w - 2) + 1) * 16 + l15, k);
#pragma unroll
        for (int n = 0; n < 4; n++) {
          bf16x8 bb = ldsfrag(xt, n * 16 + l15, k);
          acc[0][n] = MFMA16(a0, bb, acc[0][n]);
          acc[1][n] = MFMA16(a1, bb, acc[1][n]);
        }
      }
    }
    if (ks + 1 < 12) {                    // consume loads(ks+1) -> buf[b^1]
      if (ks < 10) asm volatile("s_waitcnt vmcnt(12)" ::: "memory");
      else         asm volatile("s_waitcnt vmcnt(0)" ::: "memory");
      u16* xd = &xs[b ^ 1][srow * 64];
      u16* qd = &wqs[b ^ 1][srow * 64];
      u16* vd = &wvs[b ^ 1][srow * 64];
      if (b) cvt_store(A, xd, qd, vd, scol, xsw);   // ks odd consumed A? no:
      else   cvt_store(B, xd, qd, vd, scol, xsw);   // ks even consumes B=loads(ks+1)
    }
  }

  if (w < 2) {   // q epilogue
#pragma unroll
    for (int i = 0; i < 2; i++)
#pragma unroll
      for (int n = 0; n < 4; n++) {
        const int h = n * 16 + l15;
        const float bias = bq[h];
#pragma unroll
        for (int r = 0; r < 4; r++) {
          const int sg = s0 + (2 * w + i) * 16 + lg * 4 + r;
          qbf[(size_t)sg * 64 + h] = f2bf((acc[i][n][r] + bias) * qscale);
        }
      }
  } else {       // vT epilogue
    const int b = s0 >> 12;
    const int sloc = s0 & 4095;
#pragma unroll
    for (int i = 0; i < 2; i++)
#pragma unroll
      for (int n = 0; n < 4; n++) {
        const int scg = sloc + n * 16 + l15;
#pragma unroll
        for (int r = 0; r < 4; r++) {
          const int h = (2 * (w - 2) + i) * 16 + lg * 4 + r;
          vtbf[(size_t)(b * 64 + h) * 4096 + scg] = f2bf(acc[i][n][r] + bv[h]);
        }
      }
  }
}

// ---------------- Kernel 2: flash attention (no-max softmax) ---------------
// grid (64,4) x 512thr. 8 waves: wq=w&3 owns 16 q rows, wk=w>>2 a 32-kv half.
// 3 LDS slots, prefetch distance 2, ONE raw s_barrier + vmcnt(2) per tile.
__global__ __launch_bounds__(512) void attn_k(
    const u16* __restrict__ qbf, const u16* __restrict__ vtbf,
    float* __restrict__ out)
{
  __shared__ __align__(16) u16 smem[3 * 8192 + 8 * 640];  // 3 slots(K4096+V4096) + P
  u16* pl = smem + 3 * 8192;       // [8 waves][16][40]
  const int tid = threadIdx.x;
  const int lane = tid & 63;
  const int w = tid >> 6;
  const int wq = w & 3, wk = w >> 2;
  const int l15 = lane & 15, lg = lane >> 4;
  const int b = blockIdx.y;
  const int q0 = blockIdx.x << 6;

  bf16x8 qf[2];
  {
    const u16* qr = qbf + (size_t)(b * 4096 + q0 + wq * 16 + l15) * 64 + lg * 8;
    qf[0] = *(const bf16x8*)(qr);
    qf[1] = *(const bf16x8*)(qr + 32);
  }

  f32x4 oacc[4];
#pragma unroll
  for (int i = 0; i < 4; i++) oacc[i] = (f32x4){0.f, 0.f, 0.f, 0.f};
  float lacc[4] = {0.f, 0.f, 0.f, 0.f};

  // staging: 512 thr x 16B = one 8KB tensor tile per issue
  const int o = tid << 4;                       // byte offset within a tile
  const int krow = o >> 7;                      // row (kv for K, d for V^T)
  const int ksw = o ^ ((krow & 7) << 4);        // pre-swizzled source offset
  const char* kbase = (const char*)qbf + (size_t)(b * 4096) * 128;
  const char* vbase = (const char*)vtbf + (size_t)(b * 64 + krow) * 8192 + (ksw & 127);

  const int NT = 64;
  auto stage = [&](int t, int s3) {
    char* kd = (char*)smem + s3 * 16384 + o;    // linear LDS dest
    gload_lds16(kbase + (size_t)t * 8192 + ksw, kd);
    gload_lds16(vbase + t * 128, kd + 8192);
  };

  stage(0, 0);
  stage(1, 1);

  int sl = 0, sp = 2;                           // t%3, (t+2)%3
  for (int t = 0; t < NT; ++t) {
    if (t < NT - 1) asm volatile("s_waitcnt vmcnt(2)" ::: "memory");
    else            asm volatile("s_waitcnt vmcnt(0)" ::: "memory");
    __builtin_amdgcn_s_barrier();               // tile t staged by ALL waves;
    __builtin_amdgcn_sched_barrier(0);          // all waves done with t-1
    if (t + 2 < NT) stage(t + 2, sp);           // slot (t+2)%3 == (t-1)%3: free

    const u16* kt = smem + sl * 8192;
    const u16* vt = kt + 4096;

    // QK^T: S[16 q][32 kv of this half]
    f32x4 sc0 = (f32x4){0.f, 0.f, 0.f, 0.f}, sc1 = sc0;
    __builtin_amdgcn_s_setprio(1);
#pragma unroll
    for (int j = 0; j < 2; j++) {
      const int dk = j * 32 + lg * 8;
      bf16x8 k0f = ldsfrag(kt, wk * 32 + l15, dk);
      bf16x8 k1f = ldsfrag(kt, wk * 32 + 16 + l15, dk);
      sc0 = MFMA16(qf[j], k0f, sc0);
      sc1 = MFMA16(qf[j], k1f, sc1);
    }
    __builtin_amdgcn_s_setprio(0);
    // exp (scores bounded ~4 -> no max subtraction) + row-sum over 16 lanes
    float p0[4], p1[4], rs[4];
#pragma unroll
    for (int r = 0; r < 4; r++) {
      p0[r] = __expf(sc0[r]);
      p1[r] = __expf(sc1[r]);
      rs[r] = p0[r] + p1[r];
    }
#pragma unroll
    for (int m = 1; m < 16; m <<= 1)
#pragma unroll
      for (int r = 0; r < 4; r++) rs[r] += __shfl_xor(rs[r], m, 64);
#pragma unroll
    for (int r = 0; r < 4; r++) lacc[r] += rs[r];
    // P: C-frag layout -> LDS -> A-frag layout (per-wave buffer, stride 40)
    u16* pw = pl + w * 640;
#pragma unroll
    for (int r = 0; r < 4; r++) {
      pw[(lg * 4 + r) * 40 + l15]      = f2bf(p0[r]);
      pw[(lg * 4 + r) * 40 + 16 + l15] = f2bf(p1[r]);
    }
    asm volatile("s_waitcnt lgkmcnt(0)" ::: "memory");
    bf16x8 pf = *(const bf16x8*)(pw + l15 * 40 + lg * 8);
    // PV: O[16 q][64 d] += P[16x32] * V[32x64]
    __builtin_amdgcn_s_setprio(1);
#pragma unroll
    for (int db = 0; db < 4; ++db) {
      bf16x8 vf = ldsfrag(vt, db * 16 + l15, wk * 32 + lg * 8);
      oacc[db] = MFMA16(pf, vf, oacc[db]);
    }
    __builtin_amdgcn_s_setprio(0);

    sl = (sl == 2) ? 0 : sl + 1;
    sp = (sp == 2) ? 0 : sp + 1;
  }

  // combine the two kv-halves, normalize, store
  __syncthreads();
  float* oc = (float*)smem;                 // [4][16][68]
  float* lc = oc + 4 * 16 * 68;             // [4][16]
  if (wk == 1) {
#pragma unroll
    for (int db = 0; db < 4; ++db)
#pragma unroll
      for (int r = 0; r < 4; r++)
        oc[(wq * 16 + lg * 4 + r) * 68 + db * 16 + l15] = oacc[db][r];
#pragma unroll
    for (int r = 0; r < 4; r++) lc[wq * 16 + lg * 4 + r] = lacc[r];
  }
  __syncthreads();
  if (wk == 0) {
#pragma unroll
    for (int db = 0; db < 4; ++db)
#pragma unroll
      for (int r = 0; r < 4; r++) {
        const int row = lg * 4 + r;
        const float ov = oacc[db][r] + oc[(wq * 16 + row) * 68 + db * 16 + l15];
        const float lt = lacc[r] + lc[wq * 16 + row];
        out[(size_t)(b * 4096 + q0 + wq * 16 + row) * 64 + db * 16 + l15] = ov / lt;
      }
  }
}

extern "C" void kernel_launch(void* const* d_in, const int* in_sizes, int n_in,
                              void* d_out, int out_size, void* d_ws, size_t ws_size,
                              hipStream_t stream) {
  const float* x  = (const float*)d_in[0];
  const float* Wq = (const float*)d_in[1];
  const float* bq = (const float*)d_in[2];
  const float* Wv = (const float*)d_in[3];
  const float* bv = (const float*)d_in[4];
  float* out = (float*)d_out;
  u16* qbf  = (u16*)d_ws;                       // 2 MB
  u16* vtbf = qbf + (size_t)16384 * 64;         // 2 MB
  const float qscale = 1.0f / sqrtf(sqrtf(768.0f));   // 768^-0.25 (both QK sides)
  proj_k<<<dim3(256), dim3(256), 0, stream>>>(x, Wq, bq, Wv, bv, qbf, vtbf, qscale);
  attn_k<<<dim3(64, 4), dim3(512), 0, stream>>>(qbf, vtbf, out);
}

// Round 11
// 153.033 us; speedup vs baseline: 1.0941x; 1.0822x over previous
//
#include <hip/hip_runtime.h>
#include <hip/hip_bf16.h>
#include <stdint.h>
#include <math.h>

// SelfAttention: B=4, S=4096, DK=768, H=64.  k uses q's projection (source bug),
// scale = 768^-0.5 folded as 768^-0.25 into stored q (used for both sides).
// ws: qbf [16384][64] bf16 (2MB) | vT [4][64][4096] bf16 (2MB) | l_acc f32 16384 (64KB)
// d_out is used as the O-numerator accumulator (atomicAdd), normalized in-place.

typedef unsigned short u16;
typedef __attribute__((ext_vector_type(8))) short bf16x8;
typedef __attribute__((ext_vector_type(4))) float f32x4;

#define MFMA16(a,b,c) __builtin_amdgcn_mfma_f32_16x16x32_bf16((a),(b),(c),0,0,0)

__device__ __forceinline__ u16 f2bf(float f) {
  union { float f; uint32_t u; } v; v.f = f;
  uint32_t u = v.u;
  return (u16)((u + 0x7FFFu + ((u >> 16) & 1u)) >> 16);   // RNE
}
__device__ __forceinline__ uint32_t pack2(float a, float b) {
  return (uint32_t)f2bf(a) | ((uint32_t)f2bf(b) << 16);
}

// [R][64] u16 tile, XOR swizzle: u16 idx ^= (row&7)<<3  (byte ^= (row&7)<<4)
__device__ __forceinline__ bf16x8 ldsfrag(const u16* lds, int row, int k) {
  return *(const bf16x8*)(lds + row * 64 + (k ^ ((row & 7) << 3)));
}

__device__ __forceinline__ void gload_lds16(const void* g, void* l) {
  __builtin_amdgcn_global_load_lds(
      (__attribute__((address_space(1))) void*)g,
      (__attribute__((address_space(3))) void*)l, 16, 0, 0);
}

// ---------------- Kernel 1: projections -----------------------------------
// grid 512 x 256thr, 32 s-rows per block (2 blocks/CU). Waves 0-1: q rows
// w*16..+15; waves 2-3: vT h-halves. Dist-1 register prefetch, LDS dbuf,
// ONE lgkm-only raw barrier per k-step (vmcnt never drained in-loop).
struct PR { float4 xr[2]; float4 qr[4]; float4 vr[4]; };

__device__ __forceinline__ void loadPR(PR& R, const float* xs_, const float* qs_,
                                       const float* vs_, int ks) {
  const float4* a = (const float4*)(xs_ + (ks << 6));
  const float4* b = (const float4*)(qs_ + (ks << 6));
  const float4* c = (const float4*)(vs_ + (ks << 6));
  R.xr[0] = a[0]; R.xr[1] = a[1];
  R.qr[0] = b[0]; R.qr[1] = b[1]; R.qr[2] = b[2]; R.qr[3] = b[3];
  R.vr[0] = c[0]; R.vr[1] = c[1]; R.vr[2] = c[2]; R.vr[3] = c[3];
}
__device__ __forceinline__ void cvt8(const float4& a, const float4& b, bf16x8& o) {
  o[0] = (short)f2bf(a.x); o[1] = (short)f2bf(a.y);
  o[2] = (short)f2bf(a.z); o[3] = (short)f2bf(a.w);
  o[4] = (short)f2bf(b.x); o[5] = (short)f2bf(b.y);
  o[6] = (short)f2bf(b.z); o[7] = (short)f2bf(b.w);
}

__global__ __launch_bounds__(256) void proj_k(
    const float* __restrict__ x, const float* __restrict__ Wq,
    const float* __restrict__ bq, const float* __restrict__ Wv,
    const float* __restrict__ bv, u16* __restrict__ qbf,
    u16* __restrict__ vtbf, float qscale)
{
  __shared__ __align__(16) u16 xs[2][32 * 64];
  __shared__ __align__(16) u16 wqs[2][64 * 64];
  __shared__ __align__(16) u16 wvs[2][64 * 64];
  const int tid = threadIdx.x;
  const int lane = tid & 63;
  const int w = tid >> 6;
  const int l15 = lane & 15, lg = lane >> 4;
  const int s0 = blockIdx.x * 32;

  const int xrow = tid >> 3, xcol = (tid & 7) << 3;   // 8 floats of x
  const int wrow = tid >> 2, wcol = (tid & 3) << 4;   // 16 floats of W
  const int xswz = (xrow & 7) << 3;
  const int wswz = (wrow & 7) << 3;
  const float* xsrc = x + (size_t)(s0 + xrow) * 768 + xcol;
  const float* qsrc = Wq + (size_t)wrow * 768 + wcol;
  const float* vsrc = Wv + (size_t)wrow * 768 + wcol;

  const f32x4 Z4 = {0.f, 0.f, 0.f, 0.f};
  f32x4 acc[4];
#pragma unroll
  for (int n = 0; n < 4; n++) acc[n] = Z4;

  PR A, B;
  loadPR(A, xsrc, qsrc, vsrc, 0);

  auto storePR = [&](const PR& R, int buf) {
    bf16x8 t0, t1;
    cvt8(R.xr[0], R.xr[1], t0);
    *(bf16x8*)(&xs[buf][xrow * 64] + (xcol ^ xswz)) = t0;
    cvt8(R.qr[0], R.qr[1], t0); cvt8(R.qr[2], R.qr[3], t1);
    *(bf16x8*)(&wqs[buf][wrow * 64] + (wcol ^ wswz)) = t0;
    *(bf16x8*)(&wqs[buf][wrow * 64] + ((wcol + 8) ^ wswz)) = t1;
    cvt8(R.vr[0], R.vr[1], t0); cvt8(R.vr[2], R.vr[3], t1);
    *(bf16x8*)(&wvs[buf][wrow * 64] + (wcol ^ wswz)) = t0;
    *(bf16x8*)(&wvs[buf][wrow * 64] + ((wcol + 8) ^ wswz)) = t1;
  };

  auto mfma_phase = [&](int buf) {
#pragma unroll
    for (int kk = 0; kk < 2; ++kk) {
      const int k = kk * 32 + lg * 8;
      if (w < 2) {                                  // q: A=x rows w*16.., B=Wq
        bf16x8 a = ldsfrag(xs[buf], w * 16 + l15, k);
#pragma unroll
        for (int n = 0; n < 4; n++) {
          bf16x8 bb = ldsfrag(wqs[buf], n * 16 + l15, k);
          acc[n] = MFMA16(a, bb, acc[n]);
        }
      } else {                                      // vT: A=Wv h-half, B=x^T
        const int hb = (w - 2) * 32;
        bf16x8 a0 = ldsfrag(wvs[buf], hb + l15, k);
        bf16x8 a1 = ldsfrag(wvs[buf], hb + 16 + l15, k);
        bf16x8 b0 = ldsfrag(xs[buf], l15, k);
        bf16x8 b1 = ldsfrag(xs[buf], 16 + l15, k);
        acc[0] = MFMA16(a0, b0, acc[0]);
        acc[1] = MFMA16(a0, b1, acc[1]);
        acc[2] = MFMA16(a1, b0, acc[2]);
        acc[3] = MFMA16(a1, b1, acc[3]);
      }
    }
  };

#pragma unroll
  for (int kh = 0; kh < 6; ++kh) {
    const int ks = kh * 2;
    loadPR(B, xsrc, qsrc, vsrc, ks + 1);
    storePR(A, 0);
    asm volatile("s_waitcnt lgkmcnt(0)" ::: "memory");
    __builtin_amdgcn_s_barrier();
    __builtin_amdgcn_sched_barrier(0);
    mfma_phase(0);
    if (ks + 2 < 12) loadPR(A, xsrc, qsrc, vsrc, ks + 2);
    storePR(B, 1);
    asm volatile("s_waitcnt lgkmcnt(0)" ::: "memory");
    __builtin_amdgcn_s_barrier();
    __builtin_amdgcn_sched_barrier(0);
    mfma_phase(1);
  }

  if (w < 2) {   // q epilogue: C col=h=n*16+l15, row=lg*4+r
#pragma unroll
    for (int n = 0; n < 4; n++) {
      const int h = n * 16 + l15;
      const float bias = bq[h];
#pragma unroll
      for (int r = 0; r < 4; r++) {
        const int sg = s0 + w * 16 + lg * 4 + r;
        qbf[(size_t)sg * 64 + h] = f2bf((acc[n][r] + bias) * qscale);
      }
    }
  } else {       // vT epilogue: C col=s-local=nn*16+l15, row=h-local
    const int bb = s0 >> 12;
    const int sloc = s0 & 4095;
#pragma unroll
    for (int mm = 0; mm < 2; mm++)
#pragma unroll
      for (int nn = 0; nn < 2; nn++) {
        const int scg = sloc + nn * 16 + l15;
#pragma unroll
        for (int r = 0; r < 4; r++) {
          const int h = (w - 2) * 32 + mm * 16 + lg * 4 + r;
          vtbf[(size_t)(bb * 64 + h) * 4096 + scg] = f2bf(acc[mm * 2 + nn][r] + bv[h]);
        }
      }
  }
}

// ---------------- Kernel 2: flash attention, kv-split 4 --------------------
// grid 512 x 256thr (2 blocks/CU). Block = 128 q x 1024 kv (32 tiles of 32).
// Wave w owns 32 q rows. Swapped QK^T (mfma(K,Q)) -> q is lane-local: row-sum
// deferred to ONE shfl pair at the end. 3-slot counted-vmcnt K/V staging.
// Partials combined across split-blocks via f32 atomicAdd into out + l_acc.
__global__ __launch_bounds__(256) void attn_k(
    const u16* __restrict__ qbf, const u16* __restrict__ vtbf,
    float* __restrict__ o_acc, float* __restrict__ l_acc)
{
  __shared__ __align__(16) u16 smem[3 * 4096 + 4 * 1280]; // 3 slots(K+V) + P
  u16* pbuf = smem + 12288;
  const int bid = blockIdx.x;
  const int xcd = bid & 7;
  const int batch = xcd >> 1;                 // XCD pair per batch: 2MB L2 set
  const int j = bid >> 3;
  const int qt = j >> 1;
  const int sp = ((j & 1) << 1) | (xcd & 1);  // kv quarter 0..3
  const int q0 = qt << 7;
  const int kvb = sp << 10;

  const int tid = threadIdx.x;
  const int lane = tid & 63;
  const int w = tid >> 6;
  const int l15 = lane & 15, lg = lane >> 4;
  const f32x4 Z4 = {0.f, 0.f, 0.f, 0.f};

  // Q B-frags: col=q=l15 within tile nn, k=d
  bf16x8 qf[2][2];
#pragma unroll
  for (int nn = 0; nn < 2; nn++) {
    const u16* qr = qbf + (size_t)(batch * 4096 + q0 + w * 32 + nn * 16 + l15) * 64 + lg * 8;
    qf[nn][0] = *(const bf16x8*)(qr);
    qf[nn][1] = *(const bf16x8*)(qr + 32);
  }
  asm volatile("s_waitcnt vmcnt(0)" ::: "memory");   // drain Q before counted loop

  f32x4 oacc[2][4];
#pragma unroll
  for (int nn = 0; nn < 2; nn++)
#pragma unroll
    for (int dd = 0; dd < 4; dd++) oacc[nn][dd] = Z4;
  float lacc[2] = {0.f, 0.f};

  // staging: 256thr x 16B per tensor per tile (K 4KB [32kv][64d], V 4KB [64dv][32kv])
  const int o = tid << 4;
  const int krow = o >> 7;                           // kv row of K tile
  const int vrow = o >> 6;                           // dv row of V tile
  const int koff = (o & 127) ^ ((krow & 7) << 4);    // pre-swizzled src bytes
  const int voff = (o & 63) ^ ((vrow & 3) << 4);
  const char* ksrc = (const char*)qbf +
      ((size_t)(batch * 4096 + kvb + krow)) * 128 + koff;
  const char* vsrc = (const char*)vtbf +
      ((size_t)(batch * 64 + vrow)) * 8192 + kvb * 2 + voff;

  auto stage = [&](int t, int s3) {
    char* d = (char*)smem + s3 * 8192 + o;
    gload_lds16(ksrc + (size_t)t * 4096, d);          // K: 32 rows x 128B per tile
    gload_lds16(vsrc + t * 64, d + 4096);             // V: +64B per tile along kv
  };

  stage(0, 0);
  stage(1, 1);

  int sl = 0, sp3 = 2;
  for (int t = 0; t < 32; ++t) {
    if (t < 31) asm volatile("s_waitcnt vmcnt(2)" ::: "memory");
    else        asm volatile("s_waitcnt vmcnt(0)" ::: "memory");
    __builtin_amdgcn_s_barrier();                     // tile t visible; t-1 done
    __builtin_amdgcn_sched_barrier(0);
    if (t + 2 < 32) stage(t + 2, sp3);                // slot (t+2)%3 == (t-1)%3

    const u16* kt = smem + sl * 4096;
    const u16* vt = kt + 2048;

    // S^T = K*Q: A=K[kv=l15 of mm][d], B=Q -> C col=q=l15, row=kv=lg*4+r
    bf16x8 kf[2][2];
#pragma unroll
    for (int mm = 0; mm < 2; mm++)
#pragma unroll
      for (int kk = 0; kk < 2; kk++)
        kf[mm][kk] = ldsfrag(kt, mm * 16 + l15, kk * 32 + lg * 8);
    f32x4 sc[2][2];
    __builtin_amdgcn_s_setprio(1);
#pragma unroll
    for (int mm = 0; mm < 2; mm++)
#pragma unroll
      for (int nn = 0; nn < 2; nn++) {
        f32x4 s = MFMA16(kf[mm][0], qf[nn][0], Z4);
        sc[mm][nn] = MFMA16(kf[mm][1], qf[nn][1], s);
      }
    __builtin_amdgcn_s_setprio(0);

    // exp + per-lane partial row-sum (q = nn*16+l15 is lane-local; no shuffles)
    uint32_t pk[2][2][2];
#pragma unroll
    for (int nn = 0; nn < 2; nn++) {
      float s = 0.f;
#pragma unroll
      for (int mm = 0; mm < 2; mm++) {
        float e0 = __expf(sc[mm][nn][0]), e1 = __expf(sc[mm][nn][1]);
        float e2 = __expf(sc[mm][nn][2]), e3 = __expf(sc[mm][nn][3]);
        s += (e0 + e1) + (e2 + e3);
        pk[nn][mm][0] = pack2(e0, e1);
        pk[nn][mm][1] = pack2(e2, e3);
      }
      lacc[nn] += s;
    }

    // P trip: [nn][16 q][40 kv-pad] u16 per wave; kv = mm*16+lg*4+r
    u16* pw = pbuf + w * 1280;
#pragma unroll
    for (int nn = 0; nn < 2; nn++)
#pragma unroll
      for (int mm = 0; mm < 2; mm++) {
        uint2 v; v.x = pk[nn][mm][0]; v.y = pk[nn][mm][1];
        *(uint2*)(pw + nn * 640 + l15 * 40 + mm * 16 + lg * 4) = v;
      }
    asm volatile("s_waitcnt lgkmcnt(0)" ::: "memory");
    __builtin_amdgcn_sched_barrier(0);
    bf16x8 pa[2];
#pragma unroll
    for (int nn = 0; nn < 2; nn++)
      pa[nn] = *(const bf16x8*)(pw + nn * 640 + l15 * 40 + lg * 8);

    // PV: A=P[q=l15][kv], B=V^T[dv=l15][kv] -> C col=dv, row=q
    bf16x8 vf[4];
#pragma unroll
    for (int dd = 0; dd < 4; dd++) {
      const int row = dd * 16 + l15;
      vf[dd] = *(const bf16x8*)(vt + row * 32 + ((lg * 8) ^ ((row & 3) << 3)));
    }
    __builtin_amdgcn_s_setprio(1);
#pragma unroll
    for (int nn = 0; nn < 2; nn++)
#pragma unroll
      for (int dd = 0; dd < 4; dd++)
        oacc[nn][dd] = MFMA16(pa[nn], vf[dd], oacc[nn][dd]);
    __builtin_amdgcn_s_setprio(0);

    sl = (sl == 2) ? 0 : sl + 1;
    sp3 = (sp3 == 2) ? 0 : sp3 + 1;
  }

  // deferred row-sum reduce (once) + atomic combine across kv-split blocks
#pragma unroll
  for (int nn = 0; nn < 2; nn++) {
    float s = lacc[nn];
    s += __shfl_xor(s, 16);
    s += __shfl_xor(s, 32);
    if (lg == 0)
      atomicAdd(&l_acc[batch * 4096 + q0 + w * 32 + nn * 16 + l15], s);
  }
#pragma unroll
  for (int nn = 0; nn < 2; nn++)
#pragma unroll
    for (int dd = 0; dd < 4; dd++)
#pragma unroll
      for (int r = 0; r < 4; r++) {
        const int qrow = q0 + w * 32 + nn * 16 + lg * 4 + r;
        atomicAdd(&o_acc[(size_t)(batch * 4096 + qrow) * 64 + dd * 16 + l15],
                  oacc[nn][dd][r]);
      }
}

// ---------------- Kernel 3: normalize out /= l -----------------------------
// out = 16384 rows x 64 cols = 1,048,576 floats. 16 floats/thread ->
// grid MUST be 1M/(256*16) = 256 blocks (1024 was the round-8 OOB crash).
__global__ __launch_bounds__(256) void norm_k(float* __restrict__ out,
                                              const float* __restrict__ l_acc) {
  const size_t base = ((size_t)blockIdx.x * 256 + threadIdx.x) * 16;
  const float inv = 1.0f / l_acc[base >> 6];
  float4* p = (float4*)(out + base);
#pragma unroll
  for (int j = 0; j < 4; j++) {
    float4 v = p[j];
    v.x *= inv; v.y *= inv; v.z *= inv; v.w *= inv;
    p[j] = v;
  }
}

extern "C" void kernel_launch(void* const* d_in, const int* in_sizes, int n_in,
                              void* d_out, int out_size, void* d_ws, size_t ws_size,
                              hipStream_t stream) {
  const float* x  = (const float*)d_in[0];
  const float* Wq = (const float*)d_in[1];
  const float* bq = (const float*)d_in[2];
  const float* Wv = (const float*)d_in[3];
  const float* bv = (const float*)d_in[4];
  float* out = (float*)d_out;
  u16* qbf  = (u16*)d_ws;                                   // 2 MB
  u16* vtbf = qbf + (size_t)16384 * 64;                     // 2 MB
  float* l_acc = (float*)((char*)d_ws + 4u * 1024 * 1024);  // 64 KB
  const float qscale = 1.0f / sqrtf(sqrtf(768.0f));         // 768^-0.25

  (void)hipMemsetAsync(d_out, 0, (size_t)4 * 4096 * 64 * sizeof(float), stream);
  (void)hipMemsetAsync(l_acc, 0, (size_t)16384 * sizeof(float), stream);
  proj_k<<<dim3(512), dim3(256), 0, stream>>>(x, Wq, bq, Wv, bv, qbf, vtbf, qscale);
  attn_k<<<dim3(512), dim3(256), 0, stream>>>(qbf, vtbf, out, l_acc);
  norm_k<<<dim3(256), dim3(256), 0, stream>>>(out, l_acc);
}